// Round 5
// baseline (67.683 us; speedup 1.0000x reference)
//
#include <hip/hip_runtime.h>
#include <stdint.h>

// KL pairwise: out[n,m] = ent[n] + sum_d a[n,d]*(-log b[m,d])
// N = M = 8192, D = 64, fp32 in/out.
// Round 5: prep unchanged; gemm is LDS-free — bf16 inputs (2 MB) are fully
// L2-resident, so MFMA fragments load straight from global into registers.
// No barriers, no DMA drains; waves fully independent -> store stream never
// stalls on workgroup syncs. (Common-mistake #7: don't stage L2-fit data.)

typedef __attribute__((ext_vector_type(8))) __bf16 bfx8;
typedef __attribute__((ext_vector_type(8))) unsigned short usx8;
typedef __attribute__((ext_vector_type(4))) float fx4;

__device__ __forceinline__ unsigned short f2bf(float x) {
    // round-to-nearest-even fp32 -> bf16 (finite inputs)
    unsigned int u = __float_as_uint(x);
    u += 0x7FFFu + ((u >> 16) & 1u);
    return (unsigned short)(u >> 16);
}

// blocks [0, blocksA): A rows -> ent + bf16; blocks [blocksA, ...): B rows -> -log -> bf16
__global__ __launch_bounds__(256)
void prep_kernel(const float* __restrict__ A, const float* __restrict__ B,
                 unsigned short* __restrict__ a16, unsigned short* __restrict__ lb16,
                 float* __restrict__ ent, int blocksA) {
    const int t   = threadIdx.x;
    const int rin = t >> 3;          // row within 32-row group (8 lanes per row)
    const int c8  = (t & 7) * 8;     // col start (8 floats per lane)
    if ((int)blockIdx.x < blocksA) {
        int row = blockIdx.x * 32 + rin;
        const float4* p = (const float4*)(A + (size_t)row * 64 + c8);
        float4 f0 = p[0], f1 = p[1];
        float part = f0.x*__logf(f0.x) + f0.y*__logf(f0.y) +
                     f0.z*__logf(f0.z) + f0.w*__logf(f0.w) +
                     f1.x*__logf(f1.x) + f1.y*__logf(f1.y) +
                     f1.z*__logf(f1.z) + f1.w*__logf(f1.w);
        part += __shfl_xor(part, 1);
        part += __shfl_xor(part, 2);
        part += __shfl_xor(part, 4);
        if ((t & 7) == 0) ent[row] = part;
        usx8 v;
        v[0]=f2bf(f0.x); v[1]=f2bf(f0.y); v[2]=f2bf(f0.z); v[3]=f2bf(f0.w);
        v[4]=f2bf(f1.x); v[5]=f2bf(f1.y); v[6]=f2bf(f1.z); v[7]=f2bf(f1.w);
        *(usx8*)&a16[(size_t)row * 64 + c8] = v;
    } else {
        int row = ((int)blockIdx.x - blocksA) * 32 + rin;
        const float4* p = (const float4*)(B + (size_t)row * 64 + c8);
        float4 f0 = p[0], f1 = p[1];
        usx8 v;
        v[0]=f2bf(-__logf(f0.x)); v[1]=f2bf(-__logf(f0.y));
        v[2]=f2bf(-__logf(f0.z)); v[3]=f2bf(-__logf(f0.w));
        v[4]=f2bf(-__logf(f1.x)); v[5]=f2bf(-__logf(f1.y));
        v[6]=f2bf(-__logf(f1.z)); v[7]=f2bf(-__logf(f1.w));
        *(usx8*)&lb16[(size_t)row * 64 + c8] = v;
    }
}

__global__ __launch_bounds__(256)
void gemm_kernel(const unsigned short* __restrict__ a16,
                 const unsigned short* __restrict__ lb16,
                 const float* __restrict__ ent,
                 float* __restrict__ out, int Mtot) {
    const int t = threadIdx.x, lane = t & 63, wid = t >> 6;
    const int brow = blockIdx.y, bcol = blockIdx.x;

    const unsigned short* gA = a16  + (size_t)brow * (128 * 64);
    const unsigned short* gB = lb16 + (size_t)bcol * (128 * 64);

    const int l15 = lane & 15, lk = lane >> 4;
    const int wr = (wid >> 1) * 64, wc = (wid & 1) * 64;

    // ent for this lane's 4 output-row fragments (L2-hit)
    float e[4];
#pragma unroll
    for (int i = 0; i < 4; ++i) e[i] = ent[brow * 128 + wr + i * 16 + l15];

    // Swapped-operand MFMA: A-op = -log(b) rows (-> D-row = out-col index j),
    // B-op = a rows (-> D-col = out-row). D layout: out-row = lane&15 (+i*16),
    // out-col = (lane>>4)*4 + reg (+j*16). ent preloaded as C.
    fx4 acc[4][4];   // [j = col frag][i = row frag]
#pragma unroll
    for (int j = 0; j < 4; ++j)
#pragma unroll
        for (int i = 0; i < 4; ++i) {
            acc[j][i][0] = e[i]; acc[j][i][1] = e[i];
            acc[j][i][2] = e[i]; acc[j][i][3] = e[i];
        }

#pragma unroll
    for (int ks = 0; ks < 2; ++ks) {
        const int c = ks * 4 + lk;     // 8-elem chunk index within the 64-col row
        bfx8 af[4], bg[4];
#pragma unroll
        for (int i = 0; i < 4; ++i) {
            af[i] = *(const bfx8*)&gA[(size_t)(wr + i * 16 + l15) * 64 + c * 8];
            bg[i] = *(const bfx8*)&gB[(size_t)(wc + i * 16 + l15) * 64 + c * 8];
        }
#pragma unroll
        for (int j = 0; j < 4; ++j)
#pragma unroll
            for (int i = 0; i < 4; ++i)
                acc[j][i] = __builtin_amdgcn_mfma_f32_16x16x32_bf16(
                    bg[j], af[i], acc[j][i], 0, 0, 0);
    }

    // Contiguous float4 stores; one wave covers 64 consecutive floats per row
    // across its 4 j-stores -> full 128B lines merge in L2.
#pragma unroll
    for (int i = 0; i < 4; ++i) {
        size_t row = (size_t)brow * 128 + wr + i * 16 + l15;
        float* p = out + row * (size_t)Mtot + (size_t)bcol * 128 + wc + lk * 4;
#pragma unroll
        for (int j = 0; j < 4; ++j)
            *(fx4*)(p + j * 16) = acc[j][i];
    }
}

extern "C" void kernel_launch(void* const* d_in, const int* in_sizes, int n_in,
                              void* d_out, int out_size, void* d_ws, size_t ws_size,
                              hipStream_t stream) {
    const float* a = (const float*)d_in[0];
    const float* b = (const float*)d_in[1];
    float* out = (float*)d_out;

    const int D = 64;
    const int N = in_sizes[0] / D;   // 8192
    const int M = in_sizes[1] / D;   // 8192

    // ws layout: a16 (N*64 bf16 = 1MB) | lb16 (M*64 bf16 = 1MB) | ent (N fp32 = 32KB)
    unsigned short* a16  = (unsigned short*)d_ws;
    unsigned short* lb16 = (unsigned short*)((char*)d_ws + (size_t)N * 64 * 2);
    float* ent           = (float*)((char*)d_ws + (size_t)(N + M) * 64 * 2);

    const int blocksA = N / 32, blocksB = M / 32;
    hipLaunchKernelGGL(prep_kernel, dim3(blocksA + blocksB), dim3(256), 0, stream,
                       a, b, a16, lb16, ent, blocksA);
    hipLaunchKernelGGL(gemm_kernel, dim3(M / 128, N / 128), dim3(256), 0, stream,
                       a16, lb16, ent, out, M);
}

// Round 6
// 60.629 us; speedup vs baseline: 1.1164x; 1.1164x over previous
//
#include <hip/hip_runtime.h>
#include <stdint.h>

// KL pairwise: out[n,m] = ent[n] + sum_d a[n,d]*(-log b[m,d])
// N = M = 8192, D = 64, fp32 in/out.
// Round 6: Round-4 structure + 4-tile pipelined gemm block:
//   - block keeps A panel (LDS) + A frags in regs; walks 4 B-tiles
//   - B double-buffered: stage B[t+1] via global_load_lds BEFORE compute(t),
//     so the barrier's vmcnt(0) drain is warm (DMA had a compute-phase to land)
//   - stores for tile t issued AFTER the barrier -> their drain is hidden
//     under the next tile's compute.

typedef __attribute__((ext_vector_type(8))) __bf16 bfx8;
typedef __attribute__((ext_vector_type(8))) unsigned short usx8;
typedef __attribute__((ext_vector_type(4))) float fx4;

#define AS1 __attribute__((address_space(1)))
#define AS3 __attribute__((address_space(3)))

__device__ __forceinline__ unsigned short f2bf(float x) {
    // round-to-nearest-even fp32 -> bf16 (finite inputs)
    unsigned int u = __float_as_uint(x);
    u += 0x7FFFu + ((u >> 16) & 1u);
    return (unsigned short)(u >> 16);
}

// blocks [0, blocksA): A rows -> ent + bf16; blocks [blocksA, ...): B rows -> -log -> bf16
__global__ __launch_bounds__(256)
void prep_kernel(const float* __restrict__ A, const float* __restrict__ B,
                 unsigned short* __restrict__ a16, unsigned short* __restrict__ lb16,
                 float* __restrict__ ent, int blocksA) {
    const int t   = threadIdx.x;
    const int rin = t >> 3;          // row within 32-row group (8 lanes per row)
    const int c8  = (t & 7) * 8;     // col start (8 floats per lane)
    if ((int)blockIdx.x < blocksA) {
        int row = blockIdx.x * 32 + rin;
        const float4* p = (const float4*)(A + (size_t)row * 64 + c8);
        float4 f0 = p[0], f1 = p[1];
        float part = f0.x*__logf(f0.x) + f0.y*__logf(f0.y) +
                     f0.z*__logf(f0.z) + f0.w*__logf(f0.w) +
                     f1.x*__logf(f1.x) + f1.y*__logf(f1.y) +
                     f1.z*__logf(f1.z) + f1.w*__logf(f1.w);
        part += __shfl_xor(part, 1);
        part += __shfl_xor(part, 2);
        part += __shfl_xor(part, 4);
        if ((t & 7) == 0) ent[row] = part;
        usx8 v;
        v[0]=f2bf(f0.x); v[1]=f2bf(f0.y); v[2]=f2bf(f0.z); v[3]=f2bf(f0.w);
        v[4]=f2bf(f1.x); v[5]=f2bf(f1.y); v[6]=f2bf(f1.z); v[7]=f2bf(f1.w);
        *(usx8*)&a16[(size_t)row * 64 + c8] = v;
    } else {
        int row = ((int)blockIdx.x - blocksA) * 32 + rin;
        const float4* p = (const float4*)(B + (size_t)row * 64 + c8);
        float4 f0 = p[0], f1 = p[1];
        usx8 v;
        v[0]=f2bf(-__logf(f0.x)); v[1]=f2bf(-__logf(f0.y));
        v[2]=f2bf(-__logf(f0.z)); v[3]=f2bf(-__logf(f0.w));
        v[4]=f2bf(-__logf(f1.x)); v[5]=f2bf(-__logf(f1.y));
        v[6]=f2bf(-__logf(f1.z)); v[7]=f2bf(-__logf(f1.w));
        *(usx8*)&lb16[(size_t)row * 64 + c8] = v;
    }
}

__global__ __launch_bounds__(256)
void gemm_kernel(const unsigned short* __restrict__ a16,
                 const unsigned short* __restrict__ lb16,
                 const float* __restrict__ ent,
                 float* __restrict__ out, int Mtot) {
    // LDS chunks swizzled in content: LDS chunk (row,c) holds global chunk
    // (row, c ^ (row&7)); gload_lds dest is linear (wave-uniform base+lane*16),
    // swizzle applied to the SOURCE address.
    __shared__ unsigned short sa[128 * 64];
    __shared__ unsigned short sb[2][128 * 64];

    const int t = threadIdx.x, lane = t & 63, wid = t >> 6;
    const int brow = blockIdx.y;
    const int bcol0 = blockIdx.x * 4;          // 4 consecutive B tiles per block

    const unsigned short* gA = a16 + (size_t)brow * (128 * 64);

    // ---- prologue: stage A + B[0] ----
#pragma unroll
    for (int it = 0; it < 4; ++it) {
        int dch = it * 256 + wid * 64 + lane;          // linear LDS chunk
        int row = dch >> 3, c = dch & 7;
        int sc  = row * 8 + (c ^ (row & 7));           // pre-swizzled source chunk
        __builtin_amdgcn_global_load_lds(
            (const AS1 unsigned int*)(gA + sc * 8),
            (AS3 unsigned int*)&sa[(it * 256 + wid * 64) * 8], 16, 0, 0);
    }
    {
        const unsigned short* gB = lb16 + (size_t)bcol0 * (128 * 64);
#pragma unroll
        for (int it = 0; it < 4; ++it) {
            int dch = it * 256 + wid * 64 + lane;
            int row = dch >> 3, c = dch & 7;
            int sc  = row * 8 + (c ^ (row & 7));
            __builtin_amdgcn_global_load_lds(
                (const AS1 unsigned int*)(gB + sc * 8),
                (AS3 unsigned int*)&sb[0][(it * 256 + wid * 64) * 8], 16, 0, 0);
        }
    }

    const int l15 = lane & 15, lk = lane >> 4;
    const int wr = (wid >> 1) * 64, wc = (wid & 1) * 64;

    float e[4];
#pragma unroll
    for (int i = 0; i < 4; ++i) e[i] = ent[brow * 128 + wr + i * 16 + l15];

    __syncthreads();

    // A fragments -> registers once (reused by all 4 tiles)
    bfx8 af[2][4];
#pragma unroll
    for (int ks = 0; ks < 2; ++ks)
#pragma unroll
        for (int i = 0; i < 4; ++i) {
            int c  = ks * 4 + lk;
            int ra = wr + i * 16 + l15;
            af[ks][i] = *(const bfx8*)&sa[(ra * 8 + (c ^ (ra & 7))) * 8];
        }

#pragma unroll
    for (int tt = 0; tt < 4; ++tt) {
        // stage next B tile into the other buffer (lands during compute below)
        if (tt < 3) {
            const unsigned short* gB = lb16 + (size_t)(bcol0 + tt + 1) * (128 * 64);
#pragma unroll
            for (int it = 0; it < 4; ++it) {
                int dch = it * 256 + wid * 64 + lane;
                int row = dch >> 3, c = dch & 7;
                int sc  = row * 8 + (c ^ (row & 7));
                __builtin_amdgcn_global_load_lds(
                    (const AS1 unsigned int*)(gB + sc * 8),
                    (AS3 unsigned int*)&sb[(tt + 1) & 1][(it * 256 + wid * 64) * 8],
                    16, 0, 0);
            }
        }

        // Swapped-operand MFMA on current buffer: out-row = lane&15 (+i*16),
        // out-col regs = (lane>>4)*4 + reg (+j*16). ent preloaded as C.
        const unsigned short* sbc = sb[tt & 1];
        fx4 acc[4][4];   // [j = col frag][i = row frag]
#pragma unroll
        for (int j = 0; j < 4; ++j)
#pragma unroll
            for (int i = 0; i < 4; ++i) {
                acc[j][i][0] = e[i]; acc[j][i][1] = e[i];
                acc[j][i][2] = e[i]; acc[j][i][3] = e[i];
            }
#pragma unroll
        for (int ks = 0; ks < 2; ++ks) {
            bfx8 bg[4];
#pragma unroll
            for (int j = 0; j < 4; ++j) {
                int c  = ks * 4 + lk;
                int rb = wc + j * 16 + l15;
                bg[j] = *(const bfx8*)&sbc[(rb * 8 + (c ^ (rb & 7))) * 8];
            }
#pragma unroll
            for (int j = 0; j < 4; ++j)
#pragma unroll
                for (int i = 0; i < 4; ++i)
                    acc[j][i] = __builtin_amdgcn_mfma_f32_16x16x32_bf16(
                        bg[j], af[ks][i], acc[j][i], 0, 0, 0);
        }

        // Barrier: drains the (warm) B[t+1] DMA; also releases sb[tt&1] for reuse.
        __syncthreads();

        // Stores AFTER the barrier: their completion is drained at the NEXT
        // barrier, i.e. hidden under tile tt+1's compute.
#pragma unroll
        for (int i = 0; i < 4; ++i) {
            size_t row = (size_t)brow * 128 + wr + i * 16 + l15;
            float* p = out + row * (size_t)Mtot
                     + (size_t)(bcol0 + tt) * 128 + wc + lk * 4;
#pragma unroll
            for (int j = 0; j < 4; ++j)
                *(fx4*)(p + j * 16) = acc[j][i];
        }
    }
}

extern "C" void kernel_launch(void* const* d_in, const int* in_sizes, int n_in,
                              void* d_out, int out_size, void* d_ws, size_t ws_size,
                              hipStream_t stream) {
    const float* a = (const float*)d_in[0];
    const float* b = (const float*)d_in[1];
    float* out = (float*)d_out;

    const int D = 64;
    const int N = in_sizes[0] / D;   // 8192
    const int M = in_sizes[1] / D;   // 8192

    // ws layout: a16 (N*64 bf16 = 1MB) | lb16 (M*64 bf16 = 1MB) | ent (N fp32 = 32KB)
    unsigned short* a16  = (unsigned short*)d_ws;
    unsigned short* lb16 = (unsigned short*)((char*)d_ws + (size_t)N * 64 * 2);
    float* ent           = (float*)((char*)d_ws + (size_t)(N + M) * 64 * 2);

    const int blocksA = N / 32, blocksB = M / 32;
    hipLaunchKernelGGL(prep_kernel, dim3(blocksA + blocksB), dim3(256), 0, stream,
                       a, b, a16, lb16, ent, blocksA);
    hipLaunchKernelGGL(gemm_kernel, dim3(M / 512, N / 128), dim3(256), 0, stream,
                       a16, lb16, ent, out, M);
}

// Round 7
// 50.455 us; speedup vs baseline: 1.3415x; 1.2016x over previous
//
#include <hip/hip_runtime.h>
#include <stdint.h>

// KL pairwise: out[n,m] = ent[n] + sum_d a[n,d]*(-log b[m,d])
// N = M = 8192, D = 64, fp32 in/out.
// Round 7: R4 structure, wave tile 64x32 (block 128x64) to cut VGPR under the
// 128-reg occupancy cliff -> 16 waves/CU (R4's 64x64 wave tile was ~150 VGPR
// -> likely 12 waves/CU). Store-bound kernels scale with wave count.

typedef __attribute__((ext_vector_type(8))) __bf16 bfx8;
typedef __attribute__((ext_vector_type(8))) unsigned short usx8;
typedef __attribute__((ext_vector_type(4))) float fx4;

#define AS1 __attribute__((address_space(1)))
#define AS3 __attribute__((address_space(3)))

__device__ __forceinline__ unsigned short f2bf(float x) {
    // round-to-nearest-even fp32 -> bf16 (finite inputs)
    unsigned int u = __float_as_uint(x);
    u += 0x7FFFu + ((u >> 16) & 1u);
    return (unsigned short)(u >> 16);
}

// blocks [0, blocksA): A rows -> ent + bf16; blocks [blocksA, ...): B rows -> -log -> bf16
__global__ __launch_bounds__(256)
void prep_kernel(const float* __restrict__ A, const float* __restrict__ B,
                 unsigned short* __restrict__ a16, unsigned short* __restrict__ lb16,
                 float* __restrict__ ent, int blocksA) {
    const int t   = threadIdx.x;
    const int rin = t >> 3;          // row within 32-row group (8 lanes per row)
    const int c8  = (t & 7) * 8;     // col start (8 floats per lane)
    if ((int)blockIdx.x < blocksA) {
        int row = blockIdx.x * 32 + rin;
        const float4* p = (const float4*)(A + (size_t)row * 64 + c8);
        float4 f0 = p[0], f1 = p[1];
        float part = f0.x*__logf(f0.x) + f0.y*__logf(f0.y) +
                     f0.z*__logf(f0.z) + f0.w*__logf(f0.w) +
                     f1.x*__logf(f1.x) + f1.y*__logf(f1.y) +
                     f1.z*__logf(f1.z) + f1.w*__logf(f1.w);
        part += __shfl_xor(part, 1);
        part += __shfl_xor(part, 2);
        part += __shfl_xor(part, 4);
        if ((t & 7) == 0) ent[row] = part;
        usx8 v;
        v[0]=f2bf(f0.x); v[1]=f2bf(f0.y); v[2]=f2bf(f0.z); v[3]=f2bf(f0.w);
        v[4]=f2bf(f1.x); v[5]=f2bf(f1.y); v[6]=f2bf(f1.z); v[7]=f2bf(f1.w);
        *(usx8*)&a16[(size_t)row * 64 + c8] = v;
    } else {
        int row = ((int)blockIdx.x - blocksA) * 32 + rin;
        const float4* p = (const float4*)(B + (size_t)row * 64 + c8);
        float4 f0 = p[0], f1 = p[1];
        usx8 v;
        v[0]=f2bf(-__logf(f0.x)); v[1]=f2bf(-__logf(f0.y));
        v[2]=f2bf(-__logf(f0.z)); v[3]=f2bf(-__logf(f0.w));
        v[4]=f2bf(-__logf(f1.x)); v[5]=f2bf(-__logf(f1.y));
        v[6]=f2bf(-__logf(f1.z)); v[7]=f2bf(-__logf(f1.w));
        *(usx8*)&lb16[(size_t)row * 64 + c8] = v;
    }
}

// Block tile: 128 rows (A/out rows) x 64 cols (B rows / out cols).
// 4 waves: wr = (wid>>1)*64, wc = (wid&1)*32; wave tile 64x32.
__global__ __launch_bounds__(256, 4)
void gemm_kernel(const unsigned short* __restrict__ a16,
                 const unsigned short* __restrict__ lb16,
                 const float* __restrict__ ent,
                 float* __restrict__ out, int Mtot) {
    // LDS content-swizzled: LDS chunk (row,c) holds global chunk (row, c^(row&7));
    // gload_lds dest is linear, swizzle applied to the SOURCE address.
    __shared__ unsigned short sa[128 * 64];   // 16 KB
    __shared__ unsigned short sb[64 * 64];    //  8 KB

    const int t = threadIdx.x, lane = t & 63, wid = t >> 6;
    const int brow = blockIdx.y, bcol = blockIdx.x;

    const unsigned short* gA = a16  + (size_t)brow * (128 * 64);
    const unsigned short* gB = lb16 + (size_t)bcol * (64 * 64);

    // stage A: 1024 chunks = 4 instrs/thread; B: 512 chunks = 2 instrs/thread
#pragma unroll
    for (int it = 0; it < 4; ++it) {
        int d   = it * 256 + wid * 64 + lane;
        int row = d >> 3, c = d & 7;
        int sc  = row * 8 + (c ^ (row & 7));
        __builtin_amdgcn_global_load_lds(
            (const AS1 unsigned int*)(gA + sc * 8),
            (AS3 unsigned int*)&sa[(it * 256 + wid * 64) * 8], 16, 0, 0);
    }
#pragma unroll
    for (int it = 0; it < 2; ++it) {
        int d   = it * 256 + wid * 64 + lane;
        int row = d >> 3, c = d & 7;
        int sc  = row * 8 + (c ^ (row & 7));
        __builtin_amdgcn_global_load_lds(
            (const AS1 unsigned int*)(gB + sc * 8),
            (AS3 unsigned int*)&sb[(it * 256 + wid * 64) * 8], 16, 0, 0);
    }

    const int l15 = lane & 15, lk = lane >> 4;
    const int wr = (wid >> 1) * 64;     // wave row offset (0 or 64)
    const int wc = (wid & 1) * 32;      // wave col offset (0 or 32)

    // ent for this lane's 4 row fragments (L2/LLC-hit, overlaps DMA)
    float e[4];
#pragma unroll
    for (int i = 0; i < 4; ++i) e[i] = ent[brow * 128 + wr + i * 16 + l15];

    __syncthreads();   // drains the DMA (vmcnt 0) + barrier

    // Swapped-operand MFMA: A-op = -log(b) rows -> D-col regs index out-cols;
    // B-op = a rows -> out-row = lane&15 (+i*16). ent preloaded as C.
    fx4 acc[2][4];   // [j = col frag][i = row frag]
#pragma unroll
    for (int j = 0; j < 2; ++j)
#pragma unroll
        for (int i = 0; i < 4; ++i) {
            acc[j][i][0] = e[i]; acc[j][i][1] = e[i];
            acc[j][i][2] = e[i]; acc[j][i][3] = e[i];
        }

#pragma unroll
    for (int ks = 0; ks < 2; ++ks) {
        const int c = ks * 4 + lk;
        bfx8 af[4], bg[2];
#pragma unroll
        for (int i = 0; i < 4; ++i) {
            int ra = wr + i * 16 + l15;
            af[i] = *(const bfx8*)&sa[(ra * 8 + (c ^ (ra & 7))) * 8];
        }
#pragma unroll
        for (int j = 0; j < 2; ++j) {
            int rb = wc + j * 16 + l15;
            bg[j] = *(const bfx8*)&sb[(rb * 8 + (c ^ (rb & 7))) * 8];
        }
#pragma unroll
        for (int j = 0; j < 2; ++j)
#pragma unroll
            for (int i = 0; i < 4; ++i)
                acc[j][i] = __builtin_amdgcn_mfma_f32_16x16x32_bf16(
                    bg[j], af[i], acc[j][i], 0, 0, 0);
    }

    // Stores: per row each wave covers 128 contiguous bytes (j=0,1 x lk spread).
#pragma unroll
    for (int i = 0; i < 4; ++i) {
        size_t row = (size_t)brow * 128 + wr + i * 16 + l15;
        float* p = out + row * (size_t)Mtot + (size_t)bcol * 64 + wc + lk * 4;
#pragma unroll
        for (int j = 0; j < 2; ++j)
            *(fx4*)(p + j * 16) = acc[j][i];
    }
}

extern "C" void kernel_launch(void* const* d_in, const int* in_sizes, int n_in,
                              void* d_out, int out_size, void* d_ws, size_t ws_size,
                              hipStream_t stream) {
    const float* a = (const float*)d_in[0];
    const float* b = (const float*)d_in[1];
    float* out = (float*)d_out;

    const int D = 64;
    const int N = in_sizes[0] / D;   // 8192
    const int M = in_sizes[1] / D;   // 8192

    // ws layout: a16 (N*64 bf16 = 1MB) | lb16 (M*64 bf16 = 1MB) | ent (N fp32 = 32KB)
    unsigned short* a16  = (unsigned short*)d_ws;
    unsigned short* lb16 = (unsigned short*)((char*)d_ws + (size_t)N * 64 * 2);
    float* ent           = (float*)((char*)d_ws + (size_t)(N + M) * 64 * 2);

    const int blocksA = N / 32, blocksB = M / 32;
    hipLaunchKernelGGL(prep_kernel, dim3(blocksA + blocksB), dim3(256), 0, stream,
                       a, b, a16, lb16, ent, blocksA);
    hipLaunchKernelGGL(gemm_kernel, dim3(M / 64, N / 128), dim3(256), 0, stream,
                       a16, lb16, ent, out, M);
}